// Round 9
// baseline (315.922 us; speedup 1.0000x reference)
//
#include <hip/hip_runtime.h>
#include <hip/hip_bf16.h>

#define BS 8
#define NH 4
#define NSEQ 2048
#define FIN 64
#define FOUT 32
#define CH 32
#define BHH (BS*NH)
#define NB 256
#define LOG2E 1.44269504088896340736f

typedef float f32x4 __attribute__((ext_vector_type(4)));

// ---- scratch in d_ws (floats) ----
#define WSS_SE    0
#define WSS_DE    (WSS_SE + BHH*NSEQ)
#define WSS_INVL  (WSS_DE + BHH*NSEQ)
#define WSS_TBLP  (WSS_INVL + BHH*NSEQ)           // [BHH][NB+1][33] suffix tables (vec+scalar)
#define WSS_TBLN  (WSS_TBLP + BHH*(NB+1)*33)      // [BHH][NB+1][33] prefix tables
#define WSS_FTOT  (WSS_TBLN + BHH*(NB+1)*33)      // ~740K floats = 3 MB

// ---- hp buffer (8 MB): preferred home d_ws tail; fallback = tail of attn region ----
#define BIG_HP    0                                // [BHH][NSEQ][CH]
#define BIG_TOTAL (BIG_HP + BHH*NSEQ*CH)

__device__ __forceinline__ int bin_of(float v) {
    int b = (int)((v + 8.0f) * 16.0f);
    return b < 0 ? 0 : (b > NB-1 ? NB-1 : b);
}
__device__ __forceinline__ int qbin_of(float tau) {
    int b = (int)((tau + 8.0f) * 16.0f);
    return b < 0 ? 0 : (b > NB ? NB : b);
}

// K1: h_prime = h @ w per head; s = hp.a_src, d = hp.a_dst (log2-scaled)
__global__ __launch_bounds__(256) void k1_proj(
    const float* __restrict__ h, const float* __restrict__ w,
    const float* __restrict__ asrc, const float* __restrict__ adst,
    float* __restrict__ ws, float* __restrict__ big)
{
    __shared__ float hl[64*65];
    const int b  = blockIdx.x >> 5;
    const int i0 = (blockIdx.x & 31) * 64;
    const int tid = threadIdx.x;
    const float* hsrc = h + ((size_t)b*NSEQ + i0)*FIN;
    for (int x = tid; x < 64*64; x += 256) hl[(x>>6)*65 + (x&63)] = hsrc[x];
    __syncthreads();
    const int head = __builtin_amdgcn_readfirstlane(tid >> 6);
    const int r = tid & 63;
    const int i = i0 + r;
    float acc[FOUT];
#pragma unroll
    for (int o=0;o<FOUT;o++) acc[o]=0.f;
    const float* wh = w + head*FIN*FOUT;
    for (int f=0; f<FIN; f++) {
        const float hv = hl[r*65+f];
#pragma unroll
        for (int o=0;o<FOUT;o++) acc[o] += hv * wh[f*FOUT+o];
    }
    const float* as = asrc + head*FOUT;
    const float* ad = adst + head*FOUT;
    float s=0.f, d=0.f;
#pragma unroll
    for (int o=0;o<FOUT;o++){ s += acc[o]*as[o]; d += acc[o]*ad[o]; }
    const int bh = b*NH + head;
    float* hp = big + BIG_HP + ((size_t)bh*NSEQ + i)*CH;
#pragma unroll
    for (int o=0;o<FOUT;o+=4) { f32x4 v = {acc[o],acc[o+1],acc[o+2],acc[o+3]}; *(f32x4*)(hp+o)=v; }
    ws[WSS_SE + bh*NSEQ + i] = s * LOG2E;
    ws[WSS_DE + bh*NSEQ + i] = d * LOG2E;
}

// KBIN: one block per bh. Bin-accumulate in LDS (no sort, no global round-trip),
// scan 256 bins, write TBL tables (2.2 MB total) + per-row INVL.
__global__ __launch_bounds__(1024) void kbin(
    float* __restrict__ ws, const float* __restrict__ big)
{
    __shared__ float bP[NB][33];        // 33.8 KB
    __shared__ float bN[NB][33];        // 33.8 KB
    __shared__ float wp[NSEQ];          // 8 KB
    __shared__ float wn[NSEQ];          // 8 KB
    __shared__ unsigned char binA[NSEQ];// 2 KB
    __shared__ float segP[33][16], segN[33][16], totN33[33];
    const int bh = blockIdx.x;
    const int tid = threadIdx.x;

    // phase 0: zero tables; compute weights + bins
    float* fP = (float*)bP; float* fN = (float*)bN;
    for (int x = tid; x < NB*33; x += 1024) { fP[x]=0.f; fN[x]=0.f; }
    for (int j = tid; j < NSEQ; j += 1024) {
        const float d = ws[WSS_DE + bh*NSEQ + j];
        wp[j] = __builtin_amdgcn_exp2f(d);
        wn[j] = __builtin_amdgcn_exp2f(0.2f*d);
        binA[j] = (unsigned char)bin_of(d);
    }
    __syncthreads();

    // phase 1: vector accumulate. thread = jg*32 + ch (hp reads coalesced;
    // LDS banks (33b+ch)%32 distinct across ch -> conflict-free).
    {
        const int ch = tid & 31, jg = tid >> 5;
        const float* hpb = big + BIG_HP + (size_t)bh*NSEQ*CH;
#pragma unroll 4
        for (int t=0; t<64; t++) {
            const int j = t*32 + jg;
            const float v = hpb[(size_t)j*CH + ch];
            const int b = binA[j];
            atomicAdd(&bP[b][ch], wp[j]*v);
            atomicAdd(&bN[b][ch], wn[j]*v);
        }
    }
    // phase 2: scalar accumulate
    for (int j = tid; j < NSEQ; j += 1024) {
        const int b = binA[j];
        atomicAdd(&bP[b][32], wp[j]);
        atomicAdd(&bN[b][32], wn[j]);
    }
    __syncthreads();

    // phase 3a: segment totals (16 segments x 16 bins, 33 channels)
    if (tid < 528) {
        const int ch = tid >> 4, seg = tid & 15;
        float aP=0.f, aN=0.f;
#pragma unroll
        for (int i=0;i<16;i++){ aP += bP[seg*16+i][ch]; aN += bN[seg*16+i][ch]; }
        segP[ch][seg]=aP; segN[ch][seg]=aN;
    }
    __syncthreads();
    // phase 3b: scan segment totals (suffix for P, prefix for N)
    if (tid < 33) {
        float a=0.f;
        for (int s=15;s>=0;s--){ const float t=segP[tid][s]; segP[tid][s]=a; a+=t; }
        a=0.f;
        for (int s=0;s<16;s++){ const float t=segN[tid][s]; segN[tid][s]=a; a+=t; }
        totN33[tid]=a;
    }
    __syncthreads();
    // phase 3c: in-place scans within segments (P: inclusive suffix; N: exclusive prefix)
    if (tid < 528) {
        const int ch = tid >> 4, seg = tid & 15;
        float acc = segP[ch][seg];
        for (int i=15;i>=0;i--){ acc += bP[seg*16+i][ch]; bP[seg*16+i][ch] = acc; }
        acc = segN[ch][seg];
        for (int i=0;i<16;i++){ const float t=bN[seg*16+i][ch]; bN[seg*16+i][ch]=acc; acc+=t; }
    }
    __syncthreads();

    // phase 4: write TBL tables [NB+1][33] + per-row INVL
    const size_t tb = (size_t)bh*(NB+1)*33;
    for (int x = tid; x < NB*33; x += 1024) {
        ws[WSS_TBLP + tb + x] = fP[x];
        ws[WSS_TBLN + tb + x] = fN[x];
    }
    if (tid < 33) {
        ws[WSS_TBLP + tb + NB*33 + tid] = 0.f;
        ws[WSS_TBLN + tb + NB*33 + tid] = totN33[tid];
    }
#pragma unroll
    for (int half=0; half<2; half++) {
        const int i = tid + half*1024;
        const float sp = ws[WSS_SE + bh*NSEQ + i];
        const int bq = qbin_of(-sp);
        const float Ss = (bq < NB) ? bP[bq][32] : 0.f;
        const float Ns = (bq < NB) ? bN[bq][32] : totN33[32];
        const float e1 = __builtin_amdgcn_exp2f(sp);
        const float e2 = __builtin_amdgcn_exp2f(0.2f*sp);
        ws[WSS_INVL + bh*NSEQ + i] = 1.0f / (e1*Ss + e2*Ns);
    }
}

// K3: slim prologue; outp via direct TBL lookup (L2-hot); stream 32 attn rows.
__global__ __launch_bounds__(256) void k3_stream(
    const float* __restrict__ ws, const float* __restrict__ bvec,
    float* __restrict__ outp, float* __restrict__ attn)
{
    __shared__ float E1[NSEQ], E2[NSEQ];
    __shared__ float rA[32], rB[32], rT[32], re1[32], re2[32], rinv[32];
    __shared__ int   rBQ[32];
    const int bid = blockIdx.x;                   // 2048 = 8 XCDs x 256
    const int swz = (bid & 7) * 256 + (bid >> 3); // contiguous slab per XCD
    const int bh = swz >> 6;
    const int i0 = (swz & 63) * 32;
    const int tid = threadIdx.x;
    const int wv = tid>>6, lane = tid&63;

    for (int x = tid; x < NSEQ; x += 256) {
        const float d = ws[WSS_DE + bh*NSEQ + x];
        E1[x] = __builtin_amdgcn_exp2f(d);
        E2[x] = __builtin_amdgcn_exp2f(0.2f*d);
    }
    if (tid < 32) {
        const float sp  = ws[WSS_SE   + bh*NSEQ + i0 + tid];
        const float inv = ws[WSS_INVL + bh*NSEQ + i0 + tid];
        const float e1 = __builtin_amdgcn_exp2f(sp);
        const float e2 = __builtin_amdgcn_exp2f(0.2f*sp);
        re1[tid]=e1; re2[tid]=e2; rinv[tid]=inv;
        rA[tid]=e1*inv; rB[tid]=e2*inv;
        rT[tid]=__builtin_amdgcn_exp2f(-sp);
        rBQ[tid]=qbin_of(-sp);
    }
    __syncthreads();

    {   // outp rows: 4 waves x 8 rows, TBL lookups (2.2 MB, L2-hot)
        const int half = lane >> 5, ch = lane & 31;
        const float bval = bvec[ch];
        const size_t tb = (size_t)bh*(NB+1)*33;
        const size_t ob = (size_t)bh*NSEQ;
#pragma unroll
        for (int t=0; t<4; t++) {
            const int r = wv*8 + t*2 + half;
            const int bq = rBQ[r];
            const float S = ws[WSS_TBLP + tb + (size_t)bq*33 + ch];
            const float N = ws[WSS_TBLN + tb + (size_t)bq*33 + ch];
            outp[(ob + i0 + r)*CH + ch] = (re1[r]*S + re2[r]*N)*rinv[r] + bval;
        }
    }

    // attn stream: 32 rows x 2048, zero transcendentals, exact per-element branch
    float A[8], B[8], T[8];
#pragma unroll
    for (int k=0;k<8;k++){ A[k]=rA[wv*8+k]; B[k]=rB[wv*8+k]; T[k]=rT[wv*8+k]; }
    float* rbase = attn + ((size_t)bh*NSEQ + i0 + wv*8)*NSEQ;
#pragma unroll
    for (int blk=0; blk<8; blk++) {
        const int j0 = blk*256 + lane*4;
        const f32x4 e1 = *(const f32x4*)&E1[j0];
        const f32x4 e2 = *(const f32x4*)&E2[j0];
#pragma unroll
        for (int k=0;k<8;k++) {
            f32x4 p;
            p.x = (e1.x >= T[k]) ? A[k]*e1.x : B[k]*e2.x;
            p.y = (e1.y >= T[k]) ? A[k]*e1.y : B[k]*e2.y;
            p.z = (e1.z >= T[k]) ? A[k]*e1.z : B[k]*e2.z;
            p.w = (e1.w >= T[k]) ? A[k]*e1.w : B[k]*e2.w;
            *(f32x4*)(rbase + (size_t)k*NSEQ + j0) = p;
        }
    }
}

extern "C" void kernel_launch(void* const* d_in, const int* in_sizes, int n_in,
                              void* d_out, int out_size, void* d_ws, size_t ws_size,
                              hipStream_t stream)
{
    (void)in_sizes; (void)n_in; (void)out_size;
    const float* h    = (const float*)d_in[0];
    const float* w    = (const float*)d_in[1];
    const float* asrc = (const float*)d_in[2];
    const float* adst = (const float*)d_in[3];
    const float* bvec = (const float*)d_in[4];
    float* outp = (float*)d_out;
    float* attn = outp + (size_t)BHH*NSEQ*FOUT;
    float* ws   = (float*)d_ws;

    // hp buffer: prefer d_ws (proven 2.18 GB); fallback to tail of attn region
    const size_t need_bytes = ((size_t)WSS_FTOT + BIG_TOTAL) * 4 + 1024;
    float* big = (ws_size >= need_bytes) ? (ws + WSS_FTOT)
                                         : attn + (size_t)BHH*NSEQ*NSEQ - BIG_TOTAL;

    k1_proj   <<<BS*32,  256, 0, stream>>>(h, w, asrc, adst, ws, big);
    kbin      <<<BHH,   1024, 0, stream>>>(ws, big);
    k3_stream <<<BHH*64, 256, 0, stream>>>(ws, bvec, outp, attn);
}

// Round 10
// 162.893 us; speedup vs baseline: 1.9394x; 1.9394x over previous
//
#include <hip/hip_runtime.h>
#include <hip/hip_bf16.h>

#define BS 8
#define NH 4
#define NSEQ 2048
#define FIN 64
#define FOUT 32
#define CH 32
#define BHH (BS*NH)
#define NBINS 4096
#define LOG2E 1.44269504088896340736f

typedef float f32x4 __attribute__((ext_vector_type(4)));

// ---- small scratch in d_ws ----
// float region
#define WSS_SE    0
#define WSS_DE    (WSS_SE + BHH*NSEQ)
#define WSS_INVL  (WSS_DE + BHH*NSEQ)
#define WSS_KEY   (WSS_INVL + BHH*NSEQ)          // sorted d' per (b,h)
#define WSS_E1T   (WSS_KEY + BHH*NSEQ)           // [BHH][NSEQ] 2^d'  (precomputed for k3)
#define WSS_E2T   (WSS_E1T + BHH*NSEQ)           // [BHH][NSEQ] 2^(0.2 d')
#define WSS_SUFL  (WSS_E2T + BHH*NSEQ)           // [BHH][NSEQ] scalar LOCAL suffix (per 128-chunk)
#define WSS_PREL  (WSS_SUFL + BHH*NSEQ)          // [BHH][NSEQ] scalar LOCAL prefix
#define WSS_TOTP  (WSS_PREL + BHH*NSEQ)          // [BHH][16] scalar chunk totals (P)
#define WSS_TOTN  (WSS_TOTP + BHH*16)            // [BHH][16] scalar chunk totals (N)
#define WSS_VTOTP (WSS_TOTN + BHH*16)            // [BHH][16][CH] vector chunk totals (P)
#define WSS_VTOTN (WSS_VTOTP + BHH*16*CH)        // [BHH][16][CH] vector chunk totals (N)
#define WSS_FTOT  (WSS_VTOTN + BHH*16*CH)        // ~560K floats = 2.3 MB
// int region
#define WSI_SIDX  0                               // [BHH][NSEQ] permutation
#define WSI_ITOT  (WSI_SIDX + BHH*NSEQ)

// ---- big tables: preferred home = d_ws tail; fallback = tail of attn region ----
#define BIG_HP    0                               // [BHH][NSEQ][CH]
#define BIG_SUFP  (BIG_HP + BHH*NSEQ*CH)          // [BHH][NSEQ][CH] LOCAL vector suffix
#define BIG_PREN  (BIG_SUFP + BHH*NSEQ*CH)        // [BHH][NSEQ][CH] LOCAL vector prefix
#define BIG_TOTAL (BIG_PREN + BHH*NSEQ*CH)        // 24 MB

// K1: h_prime = h @ w per head; s = hp.a_src, d = hp.a_dst (log2-scaled)
__global__ __launch_bounds__(256) void k1_proj(
    const float* __restrict__ h, const float* __restrict__ w,
    const float* __restrict__ asrc, const float* __restrict__ adst,
    float* __restrict__ ws, float* __restrict__ big)
{
    __shared__ float hl[64*65];
    const int b  = blockIdx.x >> 5;
    const int i0 = (blockIdx.x & 31) * 64;
    const int tid = threadIdx.x;
    const float* hsrc = h + ((size_t)b*NSEQ + i0)*FIN;
    for (int x = tid; x < 64*64; x += 256) hl[(x>>6)*65 + (x&63)] = hsrc[x];
    __syncthreads();
    const int head = __builtin_amdgcn_readfirstlane(tid >> 6);
    const int r = tid & 63;
    const int i = i0 + r;
    float acc[FOUT];
#pragma unroll
    for (int o=0;o<FOUT;o++) acc[o]=0.f;
    const float* wh = w + head*FIN*FOUT;
    for (int f=0; f<FIN; f++) {
        const float hv = hl[r*65+f];
#pragma unroll
        for (int o=0;o<FOUT;o++) acc[o] += hv * wh[f*FOUT+o];
    }
    const float* as = asrc + head*FOUT;
    const float* ad = adst + head*FOUT;
    float s=0.f, d=0.f;
#pragma unroll
    for (int o=0;o<FOUT;o++){ s += acc[o]*as[o]; d += acc[o]*ad[o]; }
    const int bh = b*NH + head;
    float* hp = big + BIG_HP + ((size_t)bh*NSEQ + i)*CH;
#pragma unroll
    for (int o=0;o<FOUT;o+=4) { f32x4 v = {acc[o],acc[o+1],acc[o+2],acc[o+3]}; *(f32x4*)(hp+o)=v; }
    ws[WSS_SE + bh*NSEQ + i] = s * LOG2E;
    ws[WSS_DE + bh*NSEQ + i] = d * LOG2E;
}

// KH: counting sort (4096 fixed-range bins) + precompute E1/E2 tables for k3.
__global__ __launch_bounds__(1024) void kh_sort(
    float* __restrict__ ws, int* __restrict__ wsi)
{
    __shared__ int hist[NBINS];
    __shared__ int wtot[16];
    const int bh = blockIdx.x;
    const int tid = threadIdx.x;
    const int wv = tid >> 6, lane = tid & 63;
    const float x0 = ws[WSS_DE + bh*NSEQ + tid];
    const float x1 = ws[WSS_DE + bh*NSEQ + tid + 1024];
    // E1/E2 tables (hoisted out of k3's 64-blocks-per-bh prologue)
    ws[WSS_E1T + bh*NSEQ + tid]        = __builtin_amdgcn_exp2f(x0);
    ws[WSS_E2T + bh*NSEQ + tid]        = __builtin_amdgcn_exp2f(0.2f*x0);
    ws[WSS_E1T + bh*NSEQ + tid + 1024] = __builtin_amdgcn_exp2f(x1);
    ws[WSS_E2T + bh*NSEQ + tid + 1024] = __builtin_amdgcn_exp2f(0.2f*x1);
    for (int bb=tid; bb<NBINS; bb+=1024) hist[bb]=0;
    __syncthreads();
    // fixed range ±8 (>>12 sigma of d'); clamp is monotone -> order preserved
    int b0 = (int)((x0 + 8.0f)*256.0f); b0 = b0 > NBINS-1 ? NBINS-1 : (b0 < 0 ? 0 : b0);
    int b1 = (int)((x1 + 8.0f)*256.0f); b1 = b1 > NBINS-1 ? NBINS-1 : (b1 < 0 ? 0 : b1);
    atomicAdd(&hist[b0],1); atomicAdd(&hist[b1],1);
    __syncthreads();
    int loc[4]; int tsum=0;
#pragma unroll
    for (int k=0;k<4;k++){ loc[k]=tsum; tsum += hist[tid*4+k]; }
    int inc = tsum;
#pragma unroll
    for (int off=1; off<64; off<<=1){ int v=__shfl_up(inc,off); if (lane>=off) inc+=v; }
    if (lane==63) wtot[wv]=inc;
    const int laneex = inc - tsum;
    __syncthreads();
    if (tid==0){ int a=0; for (int k=0;k<16;k++){ int v=wtot[k]; wtot[k]=a; a+=v; } }
    __syncthreads();
    const int base = wtot[wv] + laneex;
#pragma unroll
    for (int k=0;k<4;k++) hist[tid*4+k] = base + loc[k];
    __syncthreads();
    {
        int p0 = atomicAdd(&hist[b0],1);
        ws[WSS_KEY + bh*NSEQ + p0] = x0; wsi[WSI_SIDX + bh*NSEQ + p0] = tid;
        int p1 = atomicAdd(&hist[b1],1);
        ws[WSS_KEY + bh*NSEQ + p1] = x1; wsi[WSI_SIDX + bh*NSEQ + p1] = tid + 1024;
    }
}

// K2b: per (bh, 128-rank chunk): gather hp once, LOCAL scans (vector+scalar), chunk totals.
__global__ __launch_bounds__(256) void k2b(
    float* __restrict__ ws, const int* __restrict__ wsi, float* __restrict__ big)
{
    __shared__ float kk[128];
    __shared__ int   si[128];
    __shared__ float SP[128][CH];
    __shared__ float SN[128][CH];
    const int bid = blockIdx.x;
    const int bh = bid >> 4, c = bid & 15;
    const int tid = threadIdx.x, wv = tid>>6, lane = tid&63;
    if (tid < 128) {
        kk[tid] = ws[WSS_KEY + bh*NSEQ + c*128 + tid];
        si[tid] = wsi[WSI_SIDX + bh*NSEQ + c*128 + tid];
    }
    __syncthreads();
    const float* hpb = big + BIG_HP + (size_t)bh*NSEQ*CH;
    const int half = lane >> 5, ch = lane & 31;
#pragma unroll 4
    for (int t=0; t<16; t++) {
        const int rr = wv*32 + t*2 + half;
        const float dk = kk[rr];
        const float v  = hpb[(size_t)si[rr]*CH + ch];
        SP[rr][ch] = __builtin_amdgcn_exp2f(dk)      * v;
        SN[rr][ch] = __builtin_amdgcn_exp2f(0.2f*dk) * v;
    }
    __syncthreads();
    const size_t tb = (size_t)bh*NSEQ + c*128;
    if (wv == 0 && lane < CH) {
        float acc = 0.f;
        for (int rr=127; rr>=0; rr--) {
            acc += SP[rr][lane];
            big[BIG_SUFP + (tb + rr)*CH + lane] = acc;
        }
        ws[WSS_VTOTP + (bh*16 + c)*CH + lane] = acc;
    } else if (wv == 1 && lane < CH) {
        float acc = 0.f;
        for (int rr=0; rr<128; rr++) {
            big[BIG_PREN + (tb + rr)*CH + lane] = acc;
            acc += SN[rr][lane];
        }
        ws[WSS_VTOTN + (bh*16 + c)*CH + lane] = acc;
    } else if (wv == 2 && lane == 0) {
        float acc = 0.f;
        for (int rr=127; rr>=0; rr--) {
            acc += __builtin_amdgcn_exp2f(kk[rr]);
            ws[WSS_SUFL + tb + rr] = acc;
        }
        ws[WSS_TOTP + bh*16 + c] = acc;
    } else if (wv == 3 && lane == 0) {
        float acc = 0.f;
        for (int rr=0; rr<128; rr++) {
            ws[WSS_PREL + tb + rr] = acc;
            acc += __builtin_amdgcn_exp2f(0.2f*kk[rr]);
        }
        ws[WSS_TOTN + bh*16 + c] = acc;
    }
}

// K2c: per (bh, 128-row chunk): offsets in-block; binsearch -> l, inv (-> INVL); output rows.
__global__ __launch_bounds__(256) void k2c(
    float* __restrict__ ws, const float* __restrict__ big,
    const float* __restrict__ bvec, float* __restrict__ outp)
{
    __shared__ float keys[NSEQ], sufl[NSEQ], prel[NSEQ];
    __shared__ float vofP[17][CH], vofN[17][CH];
    __shared__ float sofP[17], sofN[17];
    __shared__ int   krow[128];
    __shared__ float invrow[128], e1row[128], e2row[128];
    const int bid = blockIdx.x;
    const int bh = bid >> 4, q = bid & 15;
    const int tid = threadIdx.x, wv = tid>>6, lane = tid&63;
    for (int x = tid; x < NSEQ; x += 256) {
        keys[x] = ws[WSS_KEY  + bh*NSEQ + x];
        sufl[x] = ws[WSS_SUFL + bh*NSEQ + x];
        prel[x] = ws[WSS_PREL + bh*NSEQ + x];
    }
    if (tid < CH) {
        float a = 0.f;
        for (int c=15; c>=0; c--) { vofP[c][tid] = a; a += ws[WSS_VTOTP + (bh*16+c)*CH + tid]; }
        vofP[16][tid] = 0.f;
        a = 0.f;
        for (int c=0; c<16; c++) { vofN[c][tid] = a; a += ws[WSS_VTOTN + (bh*16+c)*CH + tid]; }
        vofN[16][tid] = a;
    } else if (tid == 64) {
        float a = 0.f;
        for (int c=15; c>=0; c--) { sofP[c] = a; a += ws[WSS_TOTP + bh*16 + c]; }
        sofP[16] = 0.f;
        a = 0.f;
        for (int c=0; c<16; c++) { sofN[c] = a; a += ws[WSS_TOTN + bh*16 + c]; }
        sofN[16] = a;
    }
    __syncthreads();
    if (tid < 128) {
        const int i = q*128 + tid;
        const float sp = ws[WSS_SE + bh*NSEQ + i];
        const float tau = -sp;
        int lo=0, hi=NSEQ;
        while (lo < hi) { const int mid=(lo+hi)>>1; if (keys[mid] < tau) lo=mid+1; else hi=mid; }
        const float e1 = __builtin_amdgcn_exp2f(sp);
        const float e2 = __builtin_amdgcn_exp2f(0.2f*sp);
        const float Ss = (lo==NSEQ) ? 0.f      : sufl[lo] + sofP[lo>>7];
        const float Ns = (lo==NSEQ) ? sofN[16] : prel[lo] + sofN[lo>>7];
        const float inv = 1.0f / (e1*Ss + e2*Ns);
        ws[WSS_INVL + bh*NSEQ + i] = inv;
        krow[tid]=lo; invrow[tid]=inv; e1row[tid]=e1; e2row[tid]=e2;
    }
    __syncthreads();
    const int half = lane >> 5, ch = lane & 31;
    const float bval = bvec[ch];
    const size_t tb = (size_t)bh*NSEQ;
#pragma unroll 4
    for (int t=0; t<16; t++) {
        const int r = wv*32 + t*2 + half;
        const int k = krow[r];
        const float S = (k==NSEQ) ? 0.f          : big[BIG_SUFP + (tb + k)*CH + ch] + vofP[k>>7][ch];
        const float N = (k==NSEQ) ? vofN[16][ch] : big[BIG_PREN + (tb + k)*CH + ch] + vofN[k>>7][ch];
        outp[(tb + q*128 + r)*CH + ch] = (e1row[r]*S + e2row[r]*N)*invrow[r] + bval;
    }
}

// K3b: stream attn. Prologue = pure loads (E1/E2 precomputed); inner loop = 2 mul + 1 max.
__global__ __launch_bounds__(256) void k3b_attn(
    const float* __restrict__ ws, float* __restrict__ attn)
{
    __shared__ float E1[NSEQ], E2[NSEQ];
    __shared__ float rA[32], rB[32];
    const int bid = blockIdx.x;                   // 2048 = 8 XCDs x 256
    const int swz = (bid & 7) * 256 + (bid >> 3); // contiguous slab per XCD
    const int bh = swz >> 6;
    const int i0 = (swz & 63) * 32;
    const int tid = threadIdx.x;
    for (int x = tid; x < NSEQ; x += 256) {
        E1[x] = ws[WSS_E1T + bh*NSEQ + x];
        E2[x] = ws[WSS_E2T + bh*NSEQ + x];
    }
    if (tid < 32) {
        const float sp  = ws[WSS_SE   + bh*NSEQ + i0 + tid];
        const float inv = ws[WSS_INVL + bh*NSEQ + i0 + tid];
        rA[tid] = __builtin_amdgcn_exp2f(sp)      * inv;
        rB[tid] = __builtin_amdgcn_exp2f(0.2f*sp) * inv;
    }
    __syncthreads();
    const int wv = tid>>6, lane = tid&63;
    float A[8], B[8];
#pragma unroll
    for (int k=0;k<8;k++){ A[k]=rA[wv*8+k]; B[k]=rB[wv*8+k]; }
    float* rbase = attn + ((size_t)bh*NSEQ + i0 + wv*8)*NSEQ;
#pragma unroll
    for (int blk=0; blk<8; blk++) {
        const int j0 = blk*256 + lane*4;
        const f32x4 e1 = *(const f32x4*)&E1[j0];
        const f32x4 e2 = *(const f32x4*)&E2[j0];
#pragma unroll
        for (int k=0;k<8;k++) {
            // max(2^{t'}, 2^{0.2 t'}) * inv  ==  2^{max(t',0.2t')} * inv   (both args > 0)
            f32x4 p;
            p.x = fmaxf(A[k]*e1.x, B[k]*e2.x);
            p.y = fmaxf(A[k]*e1.y, B[k]*e2.y);
            p.z = fmaxf(A[k]*e1.z, B[k]*e2.z);
            p.w = fmaxf(A[k]*e1.w, B[k]*e2.w);
            *(f32x4*)(rbase + (size_t)k*NSEQ + j0) = p;
        }
    }
}

extern "C" void kernel_launch(void* const* d_in, const int* in_sizes, int n_in,
                              void* d_out, int out_size, void* d_ws, size_t ws_size,
                              hipStream_t stream)
{
    (void)in_sizes; (void)n_in; (void)out_size;
    const float* h    = (const float*)d_in[0];
    const float* w    = (const float*)d_in[1];
    const float* asrc = (const float*)d_in[2];
    const float* adst = (const float*)d_in[3];
    const float* bvec = (const float*)d_in[4];
    float* outp = (float*)d_out;
    float* attn = outp + (size_t)BHH*NSEQ*FOUT;
    float* ws   = (float*)d_ws;
    int*   wsi  = (int*)(ws + WSS_FTOT);

    // big tables: prefer d_ws (proven 2.18 GB); fallback = tail of attn region
    const size_t need_bytes = ((size_t)WSS_FTOT + WSI_ITOT + BIG_TOTAL) * 4 + 1024;
    float* big = (ws_size >= need_bytes) ? (float*)(wsi + WSI_ITOT)
                                         : attn + (size_t)BHH*NSEQ*NSEQ - BIG_TOTAL;

    k1_proj  <<<BS*32,   256, 0, stream>>>(h, w, asrc, adst, ws, big);
    kh_sort  <<<BHH,    1024, 0, stream>>>(ws, wsi);
    k2b      <<<BHH*16,  256, 0, stream>>>(ws, wsi, big);
    k2c      <<<BHH*16,  256, 0, stream>>>(ws, big, bvec, outp);
    k3b_attn <<<BHH*64,  256, 0, stream>>>(ws, attn);
}

// Round 11
// 158.523 us; speedup vs baseline: 1.9929x; 1.0276x over previous
//
#include <hip/hip_runtime.h>
#include <hip/hip_bf16.h>

#define BS 8
#define NH 4
#define NSEQ 2048
#define FIN 64
#define FOUT 32
#define CH 32
#define BHH (BS*NH)
#define NBINS 8192
#define LOG2E 1.44269504088896340736f

typedef float f32x4 __attribute__((ext_vector_type(4)));

// ---- small scratch in d_ws ----
// float region
#define WSS_SE    0
#define WSS_DE    (WSS_SE + BHH*NSEQ)
#define WSS_INVL  (WSS_DE + BHH*NSEQ)
#define WSS_KEY   (WSS_INVL + BHH*NSEQ)          // sorted d' per (b,h)
#define WSS_SUFL  (WSS_KEY + BHH*NSEQ)           // [BHH][NSEQ] scalar LOCAL suffix (per 128-chunk)
#define WSS_PREL  (WSS_SUFL + BHH*NSEQ)          // [BHH][NSEQ] scalar LOCAL prefix
#define WSS_TOTP  (WSS_PREL + BHH*NSEQ)          // [BHH][16] scalar chunk totals (P)
#define WSS_TOTN  (WSS_TOTP + BHH*16)            // [BHH][16] scalar chunk totals (N)
#define WSS_VTOTP (WSS_TOTN + BHH*16)            // [BHH][16][CH] vector chunk totals (P)
#define WSS_VTOTN (WSS_VTOTP + BHH*16*CH)        // [BHH][16][CH] vector chunk totals (N)
#define WSS_FTOT  (WSS_VTOTN + BHH*16*CH)        // ~ 427K floats = 1.7 MB
// int region
#define WSI_SIDX  0                               // [BHH][NSEQ] permutation

// ---- big scratch in tail of d_out's attn region ----
#define BIG_HP    0                               // [BHH][NSEQ][CH]
#define BIG_SUFP  (BIG_HP + BHH*NSEQ*CH)          // [BHH][NSEQ][CH] LOCAL vector suffix
#define BIG_PREN  (BIG_SUFP + BHH*NSEQ*CH)        // [BHH][NSEQ][CH] LOCAL vector prefix
#define BIG_TOTAL (BIG_PREN + BHH*NSEQ*CH)        // 24 MB << attn (537 MB)

// K1: h_prime = h @ w per head; s = hp.a_src, d = hp.a_dst (log2-scaled)
__global__ __launch_bounds__(256) void k1_proj(
    const float* __restrict__ h, const float* __restrict__ w,
    const float* __restrict__ asrc, const float* __restrict__ adst,
    float* __restrict__ ws, float* __restrict__ big)
{
    __shared__ float hl[64*65];
    const int b  = blockIdx.x >> 5;
    const int i0 = (blockIdx.x & 31) * 64;
    const int tid = threadIdx.x;
    const float* hsrc = h + ((size_t)b*NSEQ + i0)*FIN;
    for (int x = tid; x < 64*64; x += 256) hl[(x>>6)*65 + (x&63)] = hsrc[x];
    __syncthreads();
    const int head = __builtin_amdgcn_readfirstlane(tid >> 6);
    const int r = tid & 63;
    const int i = i0 + r;
    float acc[FOUT];
#pragma unroll
    for (int o=0;o<FOUT;o++) acc[o]=0.f;
    const float* wh = w + head*FIN*FOUT;
    for (int f=0; f<FIN; f++) {
        const float hv = hl[r*65+f];
#pragma unroll
        for (int o=0;o<FOUT;o++) acc[o] += hv * wh[f*FOUT+o];
    }
    const float* as = asrc + head*FOUT;
    const float* ad = adst + head*FOUT;
    float s=0.f, d=0.f;
#pragma unroll
    for (int o=0;o<FOUT;o++){ s += acc[o]*as[o]; d += acc[o]*ad[o]; }
    const int bh = b*NH + head;
    float* hp = big + BIG_HP + ((size_t)bh*NSEQ + i)*CH;
#pragma unroll
    for (int o=0;o<FOUT;o+=4) { f32x4 v = {acc[o],acc[o+1],acc[o+2],acc[o+3]}; *(f32x4*)(hp+o)=v; }
    ws[WSS_SE + bh*NSEQ + i] = s * LOG2E;
    ws[WSS_DE + bh*NSEQ + i] = d * LOG2E;
}

// KH: counting sort ONLY (fixed-range bins, LDS histogram+scan, scatter to global).
__global__ __launch_bounds__(1024) void kh_sort(
    float* __restrict__ ws, int* __restrict__ wsi)
{
    __shared__ int hist[NBINS];
    __shared__ int wtot[16];
    const int bh = blockIdx.x;
    const int tid = threadIdx.x;
    const int wv = tid >> 6, lane = tid & 63;
    const float x0 = ws[WSS_DE + bh*NSEQ + tid];
    const float x1 = ws[WSS_DE + bh*NSEQ + tid + 1024];
    for (int bb=tid; bb<NBINS; bb+=1024) hist[bb]=0;
    __syncthreads();
    int b0 = (int)((x0 + 8.0f)*512.0f); b0 = b0 > NBINS-1 ? NBINS-1 : (b0 < 0 ? 0 : b0);
    int b1 = (int)((x1 + 8.0f)*512.0f); b1 = b1 > NBINS-1 ? NBINS-1 : (b1 < 0 ? 0 : b1);
    atomicAdd(&hist[b0],1); atomicAdd(&hist[b1],1);
    __syncthreads();
    int loc[8]; int tsum=0;
#pragma unroll
    for (int k=0;k<8;k++){ loc[k]=tsum; tsum += hist[tid*8+k]; }
    int inc = tsum;
#pragma unroll
    for (int off=1; off<64; off<<=1){ int v=__shfl_up(inc,off); if (lane>=off) inc+=v; }
    if (lane==63) wtot[wv]=inc;
    const int laneex = inc - tsum;
    __syncthreads();
    if (tid==0){ int a=0; for (int k=0;k<16;k++){ int v=wtot[k]; wtot[k]=a; a+=v; } }
    __syncthreads();
    const int base = wtot[wv] + laneex;
#pragma unroll
    for (int k=0;k<8;k++) hist[tid*8+k] = base + loc[k];
    __syncthreads();
    {
        int p0 = atomicAdd(&hist[b0],1);
        ws[WSS_KEY + bh*NSEQ + p0] = x0; wsi[WSI_SIDX + bh*NSEQ + p0] = tid;
        int p1 = atomicAdd(&hist[b1],1);
        ws[WSS_KEY + bh*NSEQ + p1] = x1; wsi[WSI_SIDX + bh*NSEQ + p1] = tid + 1024;
    }
}

// K2b: per (bh, 128-rank chunk): gather hp once, LOCAL scans (vector+scalar), chunk totals.
__global__ __launch_bounds__(256) void k2b(
    float* __restrict__ ws, const int* __restrict__ wsi, float* __restrict__ big)
{
    __shared__ float kk[128];
    __shared__ int   si[128];
    __shared__ float SP[128][CH];
    __shared__ float SN[128][CH];
    const int bid = blockIdx.x;
    const int bh = bid >> 4, c = bid & 15;
    const int tid = threadIdx.x, wv = tid>>6, lane = tid&63;
    if (tid < 128) {
        kk[tid] = ws[WSS_KEY + bh*NSEQ + c*128 + tid];
        si[tid] = wsi[WSI_SIDX + bh*NSEQ + c*128 + tid];
    }
    __syncthreads();
    const float* hpb = big + BIG_HP + (size_t)bh*NSEQ*CH;
    const int half = lane >> 5, ch = lane & 31;
#pragma unroll 4
    for (int t=0; t<16; t++) {
        const int rr = wv*32 + t*2 + half;
        const float dk = kk[rr];
        const float v  = hpb[(size_t)si[rr]*CH + ch];
        SP[rr][ch] = __builtin_amdgcn_exp2f(dk)      * v;
        SN[rr][ch] = __builtin_amdgcn_exp2f(0.2f*dk) * v;
    }
    __syncthreads();
    const size_t tb = (size_t)bh*NSEQ + c*128;
    if (wv == 0 && lane < CH) {
        float acc = 0.f;
        for (int rr=127; rr>=0; rr--) {
            acc += SP[rr][lane];
            big[BIG_SUFP + (tb + rr)*CH + lane] = acc;
        }
        ws[WSS_VTOTP + (bh*16 + c)*CH + lane] = acc;
    } else if (wv == 1 && lane < CH) {
        float acc = 0.f;
        for (int rr=0; rr<128; rr++) {
            big[BIG_PREN + (tb + rr)*CH + lane] = acc;
            acc += SN[rr][lane];
        }
        ws[WSS_VTOTN + (bh*16 + c)*CH + lane] = acc;
    } else if (wv == 2 && lane == 0) {
        float acc = 0.f;
        for (int rr=127; rr>=0; rr--) {
            acc += __builtin_amdgcn_exp2f(kk[rr]);
            ws[WSS_SUFL + tb + rr] = acc;
        }
        ws[WSS_TOTP + bh*16 + c] = acc;
    } else if (wv == 3 && lane == 0) {
        float acc = 0.f;
        for (int rr=0; rr<128; rr++) {
            ws[WSS_PREL + tb + rr] = acc;
            acc += __builtin_amdgcn_exp2f(0.2f*kk[rr]);
        }
        ws[WSS_TOTN + bh*16 + c] = acc;
    }
}

// K2c: per (bh, 128-row chunk): offsets in-block; binsearch -> l, inv; output rows.
__global__ __launch_bounds__(256) void k2c(
    float* __restrict__ ws, const float* __restrict__ big,
    const float* __restrict__ bvec, float* __restrict__ outp)
{
    __shared__ float keys[NSEQ];
    __shared__ float sufl[NSEQ];
    __shared__ float prel[NSEQ];
    __shared__ float vofP[17][CH];
    __shared__ float vofN[17][CH];
    __shared__ float sofP[17], sofN[17];
    __shared__ int   krow[128];
    __shared__ float invrow[128], e1row[128], e2row[128];
    const int bid = blockIdx.x;
    const int bh = bid >> 4, q = bid & 15;
    const int tid = threadIdx.x, wv = tid>>6, lane = tid&63;
    for (int x = tid; x < NSEQ; x += 256) {
        keys[x] = ws[WSS_KEY  + bh*NSEQ + x];
        sufl[x] = ws[WSS_SUFL + bh*NSEQ + x];
        prel[x] = ws[WSS_PREL + bh*NSEQ + x];
    }
    if (tid < CH) {                              // vector chunk offsets
        float a = 0.f;
        for (int c=15; c>=0; c--) { vofP[c][tid] = a; a += ws[WSS_VTOTP + (bh*16+c)*CH + tid]; }
        vofP[16][tid] = 0.f;
        a = 0.f;
        for (int c=0; c<16; c++) { vofN[c][tid] = a; a += ws[WSS_VTOTN + (bh*16+c)*CH + tid]; }
        vofN[16][tid] = a;                       // grand total N
    } else if (tid == 64) {                      // scalar chunk offsets
        float a = 0.f;
        for (int c=15; c>=0; c--) { sofP[c] = a; a += ws[WSS_TOTP + bh*16 + c]; }
        sofP[16] = 0.f;
        a = 0.f;
        for (int c=0; c<16; c++) { sofN[c] = a; a += ws[WSS_TOTN + bh*16 + c]; }
        sofN[16] = a;
    }
    __syncthreads();
    if (tid < 128) {                             // binsearch + l + inv
        const int i = q*128 + tid;
        const float sp = ws[WSS_SE + bh*NSEQ + i];
        const float tau = -sp;
        int lo=0, hi=NSEQ;
        while (lo < hi) { const int mid=(lo+hi)>>1; if (keys[mid] < tau) lo=mid+1; else hi=mid; }
        const float e1 = __builtin_amdgcn_exp2f(sp);
        const float e2 = __builtin_amdgcn_exp2f(0.2f*sp);
        const float Ss = (lo==NSEQ) ? 0.f        : sufl[lo] + sofP[lo>>7];
        const float Ns = (lo==NSEQ) ? sofN[16]   : prel[lo] + sofN[lo>>7];
        const float inv = 1.0f / (e1*Ss + e2*Ns);
        ws[WSS_INVL + bh*NSEQ + i] = inv;
        krow[tid]=lo; invrow[tid]=inv; e1row[tid]=e1; e2row[tid]=e2;
    }
    __syncthreads();
    const int half = lane >> 5, ch = lane & 31;  // output rows: 4 waves x 32 rows
    const float bval = bvec[ch];
    const size_t tb = (size_t)bh*NSEQ;
#pragma unroll 4
    for (int t=0; t<16; t++) {
        const int r = wv*32 + t*2 + half;
        const int k = krow[r];
        const float S = (k==NSEQ) ? 0.f      : big[BIG_SUFP + (tb + k)*CH + ch] + vofP[k>>7][ch];
        const float N = (k==NSEQ) ? vofN[16][ch] : big[BIG_PREN + (tb + k)*CH + ch] + vofN[k>>7][ch];
        outp[(tb + q*128 + r)*CH + ch] = (e1row[r]*S + e2row[r]*N)*invrow[r] + bval;
    }
}

// K3b: stream attn, zero transcendentals in hot loop.
__global__ __launch_bounds__(256) void k3b_attn(
    const float* __restrict__ ws, float* __restrict__ attn)
{
    __shared__ float E1[NSEQ];
    __shared__ float E2[NSEQ];
    __shared__ float rA[32], rB[32], rT[32];
    const int bid = blockIdx.x;                   // 2048 = 8 XCDs x 256
    const int swz = (bid & 7) * 256 + (bid >> 3);
    const int bh = swz >> 6;
    const int i0 = (swz & 63) * 32;
    const int tid = threadIdx.x;
    for (int x = tid; x < NSEQ; x += 256) {
        const float d = ws[WSS_DE + bh*NSEQ + x];
        E1[x] = __builtin_amdgcn_exp2f(d);
        E2[x] = __builtin_amdgcn_exp2f(0.2f*d);
    }
    if (tid < 32) {
        const float sp  = ws[WSS_SE   + bh*NSEQ + i0 + tid];
        const float inv = ws[WSS_INVL + bh*NSEQ + i0 + tid];
        rA[tid] = __builtin_amdgcn_exp2f(sp)      * inv;
        rB[tid] = __builtin_amdgcn_exp2f(0.2f*sp) * inv;
        rT[tid] = __builtin_amdgcn_exp2f(-sp);
    }
    __syncthreads();
    const int wv = tid>>6, lane = tid&63;
    float A[8], B[8], T[8];
#pragma unroll
    for (int k=0;k<8;k++){ A[k]=rA[wv*8+k]; B[k]=rB[wv*8+k]; T[k]=rT[wv*8+k]; }
    float* rbase = attn + ((size_t)bh*NSEQ + i0 + wv*8)*NSEQ;
#pragma unroll
    for (int blk=0; blk<8; blk++) {
        const int j0 = blk*256 + lane*4;
        const f32x4 e1 = *(const f32x4*)&E1[j0];
        const f32x4 e2 = *(const f32x4*)&E2[j0];
#pragma unroll
        for (int k=0;k<8;k++) {
            f32x4 p;
            p.x = (e1.x >= T[k]) ? A[k]*e1.x : B[k]*e2.x;
            p.y = (e1.y >= T[k]) ? A[k]*e1.y : B[k]*e2.y;
            p.z = (e1.z >= T[k]) ? A[k]*e1.z : B[k]*e2.z;
            p.w = (e1.w >= T[k]) ? A[k]*e1.w : B[k]*e2.w;
            *(f32x4*)(rbase + (size_t)k*NSEQ + j0) = p;
        }
    }
}

extern "C" void kernel_launch(void* const* d_in, const int* in_sizes, int n_in,
                              void* d_out, int out_size, void* d_ws, size_t ws_size,
                              hipStream_t stream)
{
    (void)in_sizes; (void)n_in; (void)out_size; (void)ws_size;
    const float* h    = (const float*)d_in[0];
    const float* w    = (const float*)d_in[1];
    const float* asrc = (const float*)d_in[2];
    const float* adst = (const float*)d_in[3];
    const float* bvec = (const float*)d_in[4];
    float* outp = (float*)d_out;
    float* attn = outp + (size_t)BHH*NSEQ*FOUT;
    float* big  = attn + (size_t)BHH*NSEQ*NSEQ - BIG_TOTAL;  // tail of attn region
    float* ws   = (float*)d_ws;
    int*   wsi  = (int*)(ws + WSS_FTOT);

    k1_proj  <<<BS*32,   256, 0, stream>>>(h, w, asrc, adst, ws, big);
    kh_sort  <<<BHH,    1024, 0, stream>>>(ws, wsi);
    k2b      <<<BHH*16,  256, 0, stream>>>(ws, wsi, big);
    k2c      <<<BHH*16,  256, 0, stream>>>(ws, big, bvec, outp);
    k3b_attn <<<BHH*64,  256, 0, stream>>>(ws, attn);
}